// Round 1
// baseline (533.043 us; speedup 1.0000x reference)
//
#include <hip/hip_runtime.h>
#include <hip/hip_bf16.h>
#include <math.h>

typedef __bf16 bf16_t;
typedef __bf16 vbf4 __attribute__((ext_vector_type(4)));
typedef __bf16 vbf8 __attribute__((ext_vector_type(8)));
typedef float  vf4  __attribute__((ext_vector_type(4)));

// Problem constants
#define R_DIM 128
#define C_DIM 256
#define E_DIM 768
#define H_DIM 12
#define D_DIM 64
#define M_TOK 32768   // R*C*B
#define RD_DIM 8192   // R*D

// Workspace layout (bytes). Total = 210,763,776 B (~201 MB)
#define OFF_XB   0ull                 // Xb bf16 [32768][768] = 50331648 ; reused as CtxTok after QKV
#define OFF_Q    50331648ull          // Qh bf16 [12][256][8192]
#define OFF_K    100663296ull         // Kh bf16 [12][256][8192]
#define OFF_VT   150994944ull         // Vt bf16 [12][8192][256]
#define OFF_L    201326592ull         // L  fp32 [12][256][256] = 3145728
#define OFF_P    204472320ull         // P  bf16 [12][256][256] = 1572864
#define OFF_WQ   206045184ull         // WqT bf16 [768][768] (pre-scaled)
#define OFF_WK   207224832ull
#define OFF_WV   208404480ull
#define OFF_WO   209584128ull

// ---------------------------------------------------------------------------
// Staging: 128 rows x 64 cols bf16 tile (16 KB) via global_load_lds width=16.
// 16 chunks of 1024B; wave w handles chunks {w, w+4, w+8, w+12}.
// LDS layout [row][64] contiguous (row = 128 B) - matches lane order exactly
// (wave-uniform base + lane*16), per the global_load_lds constraint.
// ---------------------------------------------------------------------------
__device__ __forceinline__ void stage_tile128x64(const bf16_t* __restrict__ g,
                                                 int ld, int row0, int k0,
                                                 bf16_t* lds, int tid) {
  const int wave = tid >> 6;
  const int lane = tid & 63;
#pragma unroll
  for (int cc = 0; cc < 4; ++cc) {
    const int chunk = cc * 4 + wave;
    const int row = chunk * 8 + (lane >> 3);
    const bf16_t* gp = g + (size_t)(row0 + row) * ld + k0 + (lane & 7) * 8;
    bf16_t* lp = lds + chunk * 512 + lane * 8;  // elements (x2 B): chunk*1024B + lane*16B
    __builtin_amdgcn_global_load_lds(
        (const __attribute__((address_space(1))) void*)gp,
        (__attribute__((address_space(3))) void*)lp, 16, 0, 0);
  }
}

// ---------------------------------------------------------------------------
// Mainloop: C[128x128] += A[m0:m0+128, kbeg:kend] * Bt[n0:n0+128, kbeg:kend]^T
// A row-major [M][K] (k contiguous), Bt row-major [N][K] (k contiguous).
// 4 waves, each owns a 64x64 quadrant = 4x4 tiles of 16x16x32 bf16 MFMA.
// ---------------------------------------------------------------------------
__device__ __forceinline__ void gemm_mainloop(const bf16_t* __restrict__ A, int lda, int m0,
                                              const bf16_t* __restrict__ Bt, int ldb, int n0,
                                              int kbeg, int kend,
                                              bf16_t* As, bf16_t* Bs,
                                              vf4 (&acc)[4][4]) {
  const int tid = threadIdx.x;
  const int lane = tid & 63;
  const int wave = tid >> 6;
  const int wm0 = (wave >> 1) * 64;
  const int wn0 = (wave & 1) * 64;
  const int fm = lane & 15;          // m (or n) within 16-tile
  const int fk = (lane >> 4) * 8;    // k offset within 32 (8 contiguous elems)

  for (int k0 = kbeg; k0 < kend; k0 += 64) {
    stage_tile128x64(A, lda, m0, k0, As, tid);
    stage_tile128x64(Bt, ldb, n0, k0, Bs, tid);
    __syncthreads();
#pragma unroll
    for (int kk = 0; kk < 64; kk += 32) {
      vbf8 af[4], bfv[4];
#pragma unroll
      for (int mt = 0; mt < 4; ++mt)
        af[mt] = *(const vbf8*)&As[(wm0 + mt * 16 + fm) * 64 + kk + fk];
#pragma unroll
      for (int nt = 0; nt < 4; ++nt)
        bfv[nt] = *(const vbf8*)&Bs[(wn0 + nt * 16 + fm) * 64 + kk + fk];
#pragma unroll
      for (int mt = 0; mt < 4; ++mt)
#pragma unroll
        for (int nt = 0; nt < 4; ++nt)
          acc[mt][nt] = __builtin_amdgcn_mfma_f32_16x16x32_bf16(af[mt], bfv[nt],
                                                                acc[mt][nt], 0, 0, 0);
    }
    __syncthreads();
  }
}

__device__ __forceinline__ void zero_acc(vf4 (&acc)[4][4]) {
  const vf4 z = {0.f, 0.f, 0.f, 0.f};
#pragma unroll
  for (int mt = 0; mt < 4; ++mt)
#pragma unroll
    for (int nt = 0; nt < 4; ++nt) acc[mt][nt] = z;
}

// ---------------------------------------------------------------------------
// Pack kernels
// ---------------------------------------------------------------------------
__global__ __launch_bounds__(256) void pack_x(const float* __restrict__ x,
                                              bf16_t* __restrict__ Xb) {
  const size_t idx = (size_t)blockIdx.x * 256 + threadIdx.x;  // < 6291456 float4s
  const float4 v = ((const float4*)x)[idx];
  vbf4 o;
  o[0] = (bf16_t)v.x; o[1] = (bf16_t)v.y; o[2] = (bf16_t)v.z; o[3] = (bf16_t)v.w;
  ((vbf4*)Xb)[idx] = o;
}

__global__ __launch_bounds__(256) void pack_w(const float* __restrict__ wq,
                                              const float* __restrict__ wk,
                                              const float* __restrict__ wv,
                                              const float* __restrict__ wo,
                                              bf16_t* __restrict__ Wq, bf16_t* __restrict__ Wk,
                                              bf16_t* __restrict__ Wv, bf16_t* __restrict__ Wo,
                                              float scaling) {
  const int idx = blockIdx.x * 256 + threadIdx.x;  // 0..589823
  const int wid = blockIdx.y;
  const float* src = (wid == 0) ? wq : (wid == 1) ? wk : (wid == 2) ? wv : wo;
  bf16_t* dst = (wid == 0) ? Wq : (wid == 1) ? Wk : (wid == 2) ? Wv : Wo;
  const int n = idx / 768;
  const int k = idx - n * 768;
  float v = src[k * 768 + n];  // transpose: Wt[n][k] = w[k][n]
  if (wid == 0) v *= scaling;  // fold q scaling into Wq
  dst[idx] = (bf16_t)v;
}

// ---------------------------------------------------------------------------
// QKV projection: z=0 -> Q head-major, z=1 -> K head-major, z=2 -> V transposed
// ---------------------------------------------------------------------------
__global__ __launch_bounds__(256) void qkv_gemm(const bf16_t* __restrict__ Xb,
                                                const bf16_t* __restrict__ Wq,
                                                const bf16_t* __restrict__ Wk,
                                                const bf16_t* __restrict__ Wv,
                                                const float* __restrict__ bq,
                                                const float* __restrict__ bk,
                                                const float* __restrict__ bv,
                                                bf16_t* __restrict__ Qh,
                                                bf16_t* __restrict__ Kh,
                                                bf16_t* __restrict__ Vt,
                                                float scaling) {
  __shared__ __align__(16) bf16_t As[128 * 64];
  __shared__ __align__(16) bf16_t Bs[128 * 64];
  const int m0 = blockIdx.x * 128;
  const int n0 = blockIdx.y * 128;
  const int z = blockIdx.z;
  const bf16_t* W = (z == 0) ? Wq : (z == 1) ? Wk : Wv;
  vf4 acc[4][4];
  zero_acc(acc);
  gemm_mainloop(Xb, 768, m0, W, 768, n0, 0, 768, As, Bs, acc);

  const int lane = threadIdx.x & 63;
  const int wave = threadIdx.x >> 6;
  const int wm0 = (wave >> 1) * 64;
  const int wn0 = (wave & 1) * 64;
  const int col = lane & 15;
  const int rq = (lane >> 4) * 4;
  const float* bias = (z == 0) ? bq : (z == 1) ? bk : bv;
  const float bsc = (z == 0) ? scaling : 1.0f;

  if (z < 2) {
    bf16_t* O = (z == 0) ? Qh : Kh;
#pragma unroll
    for (int mt = 0; mt < 4; ++mt) {
#pragma unroll
      for (int nt = 0; nt < 4; ++nt) {
        const int n = n0 + wn0 + nt * 16 + col;
        const int h = n >> 6, d = n & 63;
        const float bb = bias[n] * bsc;
#pragma unroll
        for (int i = 0; i < 4; ++i) {
          const int m = m0 + wm0 + mt * 16 + rq + i;
          const int r = m >> 8, c = m & 255;
          O[(size_t)(h * 256 + c) * 8192 + (r << 6) + d] = (bf16_t)(acc[mt][nt][i] + bb);
        }
      }
    }
  } else {
    // Vt[h][r*64+d][c]: 4 acc regs are 4 consecutive c -> packed 8B store
#pragma unroll
    for (int mt = 0; mt < 4; ++mt) {
      const int mb = m0 + wm0 + mt * 16 + rq;
      const int r = mb >> 8, c = mb & 255;
#pragma unroll
      for (int nt = 0; nt < 4; ++nt) {
        const int n = n0 + wn0 + nt * 16 + col;
        const int h = n >> 6, d = n & 63;
        const float bb = bias[n];
        vbf4 pk;
#pragma unroll
        for (int i = 0; i < 4; ++i) pk[i] = (bf16_t)(acc[mt][nt][i] + bb);
        *(vbf4*)&Vt[(size_t)h * 2097152 + ((size_t)((r << 6) + d)) * 256 + c] = pk;
      }
    }
  }
}

// ---------------------------------------------------------------------------
// Logits: L[h][i][j] = sum_rd Qh[h][i][rd]*Kh[h][j][rd], split-K x4 with atomics
// ---------------------------------------------------------------------------
__global__ __launch_bounds__(256) void logits_gemm(const bf16_t* __restrict__ Qh,
                                                   const bf16_t* __restrict__ Kh,
                                                   float* __restrict__ L) {
  __shared__ __align__(16) bf16_t As[128 * 64];
  __shared__ __align__(16) bf16_t Bs[128 * 64];
  const int m0 = blockIdx.x * 128;
  const int n0 = blockIdx.y * 128;
  const int h = blockIdx.z >> 2;
  const int kseg = blockIdx.z & 3;
  const bf16_t* A = Qh + (size_t)h * (256 * 8192);
  const bf16_t* B = Kh + (size_t)h * (256 * 8192);
  vf4 acc[4][4];
  zero_acc(acc);
  gemm_mainloop(A, 8192, m0, B, 8192, n0, kseg * 2048, kseg * 2048 + 2048, As, Bs, acc);

  const int lane = threadIdx.x & 63;
  const int wave = threadIdx.x >> 6;
  const int wm0 = (wave >> 1) * 64;
  const int wn0 = (wave & 1) * 64;
  const int col = lane & 15;
  const int rq = (lane >> 4) * 4;
  float* Lh = L + (size_t)h * 65536;
#pragma unroll
  for (int mt = 0; mt < 4; ++mt)
#pragma unroll
    for (int nt = 0; nt < 4; ++nt) {
      const int n = n0 + wn0 + nt * 16 + col;
#pragma unroll
      for (int i = 0; i < 4; ++i) {
        const int m = m0 + wm0 + mt * 16 + rq + i;
        atomicAdd(&Lh[(size_t)m * 256 + n], acc[mt][nt][i]);
      }
    }
}

// ---------------------------------------------------------------------------
// Softmax over j: one wave per row (12*256 = 3072 rows)
// ---------------------------------------------------------------------------
__global__ __launch_bounds__(256) void softmax_k(const float* __restrict__ L,
                                                 bf16_t* __restrict__ P) {
  const int row = blockIdx.x * 4 + (threadIdx.x >> 6);
  const int lane = threadIdx.x & 63;
  const float4 v4 = ((const float4*)(L + (size_t)row * 256))[lane];
  float a = v4.x, b = v4.y, c = v4.z, d = v4.w;
  float mx = fmaxf(fmaxf(a, b), fmaxf(c, d));
#pragma unroll
  for (int off = 32; off; off >>= 1) mx = fmaxf(mx, __shfl_xor(mx, off));
  a = expf(a - mx); b = expf(b - mx); c = expf(c - mx); d = expf(d - mx);
  float s = a + b + c + d;
#pragma unroll
  for (int off = 32; off; off >>= 1) s += __shfl_xor(s, off);
  const float inv = 1.0f / s;
  vbf4 o;
  o[0] = (bf16_t)(a * inv); o[1] = (bf16_t)(b * inv);
  o[2] = (bf16_t)(c * inv); o[3] = (bf16_t)(d * inv);
  ((vbf4*)(P + (size_t)row * 256))[lane] = o;
}

// ---------------------------------------------------------------------------
// Context: Ctx[i][rd] = sum_j P[h][i][j] * Vt[h][rd][j]; written token-major
// ---------------------------------------------------------------------------
__global__ __launch_bounds__(256) void ctx_gemm(const bf16_t* __restrict__ P,
                                                const bf16_t* __restrict__ Vt,
                                                bf16_t* __restrict__ CtxTok) {
  __shared__ __align__(16) bf16_t As[128 * 64];
  __shared__ __align__(16) bf16_t Bs[128 * 64];
  const int m0 = blockIdx.x * 128;   // i (= c), M=256
  const int n0 = blockIdx.y * 128;   // rd, N=8192
  const int h = blockIdx.z;
  const bf16_t* A = P + (size_t)h * 65536;
  const bf16_t* B = Vt + (size_t)h * 2097152;
  vf4 acc[4][4];
  zero_acc(acc);
  gemm_mainloop(A, 256, m0, B, 256, n0, 0, 256, As, Bs, acc);

  const int lane = threadIdx.x & 63;
  const int wave = threadIdx.x >> 6;
  const int wm0 = (wave >> 1) * 64;
  const int wn0 = (wave & 1) * 64;
  const int col = lane & 15;
  const int rq = (lane >> 4) * 4;
#pragma unroll
  for (int mt = 0; mt < 4; ++mt)
#pragma unroll
    for (int nt = 0; nt < 4; ++nt) {
      const int n = n0 + wn0 + nt * 16 + col;
      const int r = n >> 6, d = n & 63;
#pragma unroll
      for (int i = 0; i < 4; ++i) {
        const int m = m0 + wm0 + mt * 16 + rq + i;  // c
        CtxTok[(size_t)((r << 8) + m) * 768 + (h << 6) + d] = (bf16_t)acc[mt][nt][i];
      }
    }
}

// ---------------------------------------------------------------------------
// Output projection: out = Ctx @ wo + bo (fp32 out)
// ---------------------------------------------------------------------------
__global__ __launch_bounds__(256) void out_gemm(const bf16_t* __restrict__ Ctx,
                                                const bf16_t* __restrict__ Wo,
                                                const float* __restrict__ bo,
                                                float* __restrict__ Out) {
  __shared__ __align__(16) bf16_t As[128 * 64];
  __shared__ __align__(16) bf16_t Bs[128 * 64];
  const int m0 = blockIdx.x * 128;
  const int n0 = blockIdx.y * 128;
  vf4 acc[4][4];
  zero_acc(acc);
  gemm_mainloop(Ctx, 768, m0, Wo, 768, n0, 0, 768, As, Bs, acc);

  const int lane = threadIdx.x & 63;
  const int wave = threadIdx.x >> 6;
  const int wm0 = (wave >> 1) * 64;
  const int wn0 = (wave & 1) * 64;
  const int col = lane & 15;
  const int rq = (lane >> 4) * 4;
#pragma unroll
  for (int mt = 0; mt < 4; ++mt)
#pragma unroll
    for (int nt = 0; nt < 4; ++nt) {
      const int n = n0 + wn0 + nt * 16 + col;
      const float bb = bo[n];
#pragma unroll
      for (int i = 0; i < 4; ++i) {
        const int m = m0 + wm0 + mt * 16 + rq + i;
        Out[(size_t)m * 768 + n] = acc[mt][nt][i] + bb;
      }
    }
}

// ---------------------------------------------------------------------------
extern "C" void kernel_launch(void* const* d_in, const int* in_sizes, int n_in,
                              void* d_out, int out_size, void* d_ws, size_t ws_size,
                              hipStream_t stream) {
  const float* x  = (const float*)d_in[0];
  const float* wq = (const float*)d_in[1];
  const float* bq = (const float*)d_in[2];
  const float* wk = (const float*)d_in[3];
  const float* bk = (const float*)d_in[4];
  const float* wv = (const float*)d_in[5];
  const float* bv = (const float*)d_in[6];
  const float* wo = (const float*)d_in[7];
  const float* bo = (const float*)d_in[8];
  float* out = (float*)d_out;

  char* ws = (char*)d_ws;
  bf16_t* Xb  = (bf16_t*)(ws + OFF_XB);
  bf16_t* Ctx = (bf16_t*)(ws + OFF_XB);   // alias: Xb dead after QKV
  bf16_t* Qh  = (bf16_t*)(ws + OFF_Q);
  bf16_t* Kh  = (bf16_t*)(ws + OFF_K);
  bf16_t* Vt  = (bf16_t*)(ws + OFF_VT);
  float*  L   = (float*)(ws + OFF_L);
  bf16_t* P   = (bf16_t*)(ws + OFF_P);
  bf16_t* Wq  = (bf16_t*)(ws + OFF_WQ);
  bf16_t* Wk  = (bf16_t*)(ws + OFF_WK);
  bf16_t* Wv  = (bf16_t*)(ws + OFF_WV);
  bf16_t* Wo  = (bf16_t*)(ws + OFF_WO);

  const float scaling = 0.125f / sqrtf(128.0f);  // D^-0.5 / sqrt(R)

  hipMemsetAsync(L, 0, (size_t)12 * 256 * 256 * 4, stream);
  pack_x<<<24576, 256, 0, stream>>>(x, Xb);                       // 25.2M elems / 4
  pack_w<<<dim3(2304, 4), 256, 0, stream>>>(wq, wk, wv, wo, Wq, Wk, Wv, Wo, scaling);
  qkv_gemm<<<dim3(256, 6, 3), 256, 0, stream>>>(Xb, Wq, Wk, Wv, bq, bk, bv, Qh, Kh, Vt, scaling);
  logits_gemm<<<dim3(2, 2, 48), 256, 0, stream>>>(Qh, Kh, L);     // z = h*4 + kseg
  softmax_k<<<768, 256, 0, stream>>>(L, P);
  ctx_gemm<<<dim3(2, 64, 12), 256, 0, stream>>>(P, Vt, Ctx);
  out_gemm<<<dim3(256, 6, 1), 256, 0, stream>>>(Ctx, Wo, bo, out);

  (void)in_sizes; (void)n_in; (void)out_size; (void)ws_size;
}

// Round 2
// 498.718 us; speedup vs baseline: 1.0688x; 1.0688x over previous
//
#include <hip/hip_runtime.h>
#include <hip/hip_bf16.h>
#include <math.h>

typedef __bf16 bf16_t;
typedef __bf16 vbf4 __attribute__((ext_vector_type(4)));
typedef __bf16 vbf8 __attribute__((ext_vector_type(8)));
typedef float  vf4  __attribute__((ext_vector_type(4)));

// Workspace layout (bytes). Total = 210,763,776 B (~201 MB)
#define OFF_XB   0ull                 // Xb bf16 [32768][768]; reused as CtxTok after QKV
#define OFF_Q    50331648ull          // Qh bf16 [12][256][8192]
#define OFF_K    100663296ull         // Kh bf16 [12][256][8192]
#define OFF_VT   150994944ull         // Vt bf16 [12][8192][256]
#define OFF_L    201326592ull         // L  fp32 [12][256][256]
#define OFF_P    204472320ull         // P  bf16 [12][256][256]
#define OFF_WQ   206045184ull         // WqT bf16 [768][768] (pre-scaled)
#define OFF_WK   207224832ull
#define OFF_WV   208404480ull
#define OFF_WO   209584128ull

// ---------------------------------------------------------------------------
// Staging: 128 rows x 64 cols bf16 tile (16 KB) via global_load_lds width=16.
// XOR-swizzled: LDS[r][chunk j] holds global chunk (j ^ (r&7)). Source lanes
// within a row-group still cover the same 128 B segment (coalesced); LDS
// destination stays lane-contiguous as global_load_lds requires.
// ---------------------------------------------------------------------------
__device__ __forceinline__ void stage_tile128x64(const bf16_t* __restrict__ g,
                                                 int ld, int row0, int k0,
                                                 bf16_t* lds, int tid) {
  const int wave = tid >> 6;
  const int lane = tid & 63;
  const int js = (lane & 7) ^ (lane >> 3);   // swizzled source chunk (row&7 == lane>>3)
#pragma unroll
  for (int cc = 0; cc < 4; ++cc) {
    const int chunk = cc * 4 + wave;
    const int row = chunk * 8 + (lane >> 3);
    const bf16_t* gp = g + (size_t)(row0 + row) * ld + k0 + js * 8;
    bf16_t* lp = lds + chunk * 512 + lane * 8;
    __builtin_amdgcn_global_load_lds(
        (const __attribute__((address_space(1))) void*)gp,
        (__attribute__((address_space(3))) void*)lp, 16, 0, 0);
  }
}

// Swizzled fragment read: 8 contiguous bf16 (one 16 B chunk) of row rr at k=ko
__device__ __forceinline__ vbf8 lds_frag(const bf16_t* s, int rr, int ko) {
  const int c = (ko >> 3) ^ (rr & 7);
  return *(const vbf8*)&s[rr * 64 + (c << 3)];
}

// ---------------------------------------------------------------------------
// Mainloop: C[128x128] += A[m0:, kbeg:kend] * Bt[n0:, kbeg:kend]^T
// A row-major [M][K], Bt row-major [N][K]. 4 waves x (64x64 quadrant of 4x4
// 16x16x32 bf16 MFMA tiles).
// ---------------------------------------------------------------------------
__device__ __forceinline__ void gemm_mainloop(const bf16_t* __restrict__ A, int lda, int m0,
                                              const bf16_t* __restrict__ Bt, int ldb, int n0,
                                              int kbeg, int kend,
                                              bf16_t* As, bf16_t* Bs,
                                              vf4 (&acc)[4][4]) {
  const int tid = threadIdx.x;
  const int lane = tid & 63;
  const int wave = tid >> 6;
  const int wm0 = (wave >> 1) * 64;
  const int wn0 = (wave & 1) * 64;
  const int fm = lane & 15;
  const int fk = (lane >> 4) * 8;

  for (int k0 = kbeg; k0 < kend; k0 += 64) {
    stage_tile128x64(A, lda, m0, k0, As, tid);
    stage_tile128x64(Bt, ldb, n0, k0, Bs, tid);
    __syncthreads();
#pragma unroll
    for (int kk = 0; kk < 64; kk += 32) {
      vbf8 af[4], bfv[4];
#pragma unroll
      for (int mt = 0; mt < 4; ++mt)
        af[mt] = lds_frag(As, wm0 + mt * 16 + fm, kk + fk);
#pragma unroll
      for (int nt = 0; nt < 4; ++nt)
        bfv[nt] = lds_frag(Bs, wn0 + nt * 16 + fm, kk + fk);
#pragma unroll
      for (int mt = 0; mt < 4; ++mt)
#pragma unroll
        for (int nt = 0; nt < 4; ++nt)
          acc[mt][nt] = __builtin_amdgcn_mfma_f32_16x16x32_bf16(af[mt], bfv[nt],
                                                                acc[mt][nt], 0, 0, 0);
    }
    __syncthreads();
  }
}

__device__ __forceinline__ void zero_acc(vf4 (&acc)[4][4]) {
  const vf4 z = {0.f, 0.f, 0.f, 0.f};
#pragma unroll
  for (int mt = 0; mt < 4; ++mt)
#pragma unroll
    for (int nt = 0; nt < 4; ++nt) acc[mt][nt] = z;
}

// ---------------------------------------------------------------------------
// Pack kernels
// ---------------------------------------------------------------------------
__global__ __launch_bounds__(256) void pack_x(const float* __restrict__ x,
                                              bf16_t* __restrict__ Xb) {
  const size_t idx = (size_t)blockIdx.x * 256 + threadIdx.x;
  const float4 v = ((const float4*)x)[idx];
  vbf4 o;
  o[0] = (bf16_t)v.x; o[1] = (bf16_t)v.y; o[2] = (bf16_t)v.z; o[3] = (bf16_t)v.w;
  ((vbf4*)Xb)[idx] = o;
}

__global__ __launch_bounds__(256) void pack_w(const float* __restrict__ wq,
                                              const float* __restrict__ wk,
                                              const float* __restrict__ wv,
                                              const float* __restrict__ wo,
                                              bf16_t* __restrict__ Wq, bf16_t* __restrict__ Wk,
                                              bf16_t* __restrict__ Wv, bf16_t* __restrict__ Wo,
                                              float scaling) {
  const int idx = blockIdx.x * 256 + threadIdx.x;
  const int wid = blockIdx.y;
  const float* src = (wid == 0) ? wq : (wid == 1) ? wk : (wid == 2) ? wv : wo;
  bf16_t* dst = (wid == 0) ? Wq : (wid == 1) ? Wk : (wid == 2) ? Wv : Wo;
  const int n = idx / 768;
  const int k = idx - n * 768;
  float v = src[k * 768 + n];  // transpose
  if (wid == 0) v *= scaling;
  dst[idx] = (bf16_t)v;
}

// ---------------------------------------------------------------------------
// QKV projection, 1-D grid: bx -> (m, n, z); 18 blocks sharing an A-tile are
// adjacent in dispatch so the tile is served from L2/L3, not HBM.
// z=0 -> Q head-major, z=1 -> K head-major, z=2 -> V transposed
// ---------------------------------------------------------------------------
__global__ __launch_bounds__(256) void qkv_gemm(const bf16_t* __restrict__ Xb,
                                                const bf16_t* __restrict__ Wq,
                                                const bf16_t* __restrict__ Wk,
                                                const bf16_t* __restrict__ Wv,
                                                const float* __restrict__ bq,
                                                const float* __restrict__ bk,
                                                const float* __restrict__ bv,
                                                bf16_t* __restrict__ Qh,
                                                bf16_t* __restrict__ Kh,
                                                bf16_t* __restrict__ Vt,
                                                float scaling) {
  __shared__ __align__(16) bf16_t As[128 * 64];
  __shared__ __align__(16) bf16_t Bs[128 * 64];
  const int bx = blockIdx.x;
  const int m_idx = bx / 18;
  const int rem = bx - m_idx * 18;
  const int n_idx = rem / 3;
  const int z = rem - n_idx * 3;
  const int m0 = m_idx * 128;
  const int n0 = n_idx * 128;
  const bf16_t* W = (z == 0) ? Wq : (z == 1) ? Wk : Wv;
  vf4 acc[4][4];
  zero_acc(acc);
  gemm_mainloop(Xb, 768, m0, W, 768, n0, 0, 768, As, Bs, acc);

  const int lane = threadIdx.x & 63;
  const int wave = threadIdx.x >> 6;
  const int wm0 = (wave >> 1) * 64;
  const int wn0 = (wave & 1) * 64;
  const int col = lane & 15;
  const int rq = (lane >> 4) * 4;
  const float* bias = (z == 0) ? bq : (z == 1) ? bk : bv;
  const float bsc = (z == 0) ? scaling : 1.0f;

  if (z < 2) {
    bf16_t* O = (z == 0) ? Qh : Kh;
#pragma unroll
    for (int mt = 0; mt < 4; ++mt) {
#pragma unroll
      for (int nt = 0; nt < 4; ++nt) {
        const int n = n0 + wn0 + nt * 16 + col;
        const int h = n >> 6, d = n & 63;
        const float bb = bias[n] * bsc;
#pragma unroll
        for (int i = 0; i < 4; ++i) {
          const int m = m0 + wm0 + mt * 16 + rq + i;
          const int r = m >> 8, c = m & 255;
          O[(size_t)(h * 256 + c) * 8192 + (r << 6) + d] = (bf16_t)(acc[mt][nt][i] + bb);
        }
      }
    }
  } else {
#pragma unroll
    for (int mt = 0; mt < 4; ++mt) {
      const int mb = m0 + wm0 + mt * 16 + rq;
      const int r = mb >> 8, c = mb & 255;
#pragma unroll
      for (int nt = 0; nt < 4; ++nt) {
        const int n = n0 + wn0 + nt * 16 + col;
        const int h = n >> 6, d = n & 63;
        const float bb = bias[n];
        vbf4 pk;
#pragma unroll
        for (int i = 0; i < 4; ++i) pk[i] = (bf16_t)(acc[mt][nt][i] + bb);
        *(vbf4*)&Vt[(size_t)h * 2097152 + ((size_t)((r << 6) + d)) * 256 + c] = pk;
      }
    }
  }
}

// ---------------------------------------------------------------------------
// Logits: L[h][i][j] = sum_rd Qh[h][i][rd]*Kh[h][j][rd], split-K x8 + atomics
// grid (nx=2, my=2, z = h*8+kseg)
// ---------------------------------------------------------------------------
__global__ __launch_bounds__(256) void logits_gemm(const bf16_t* __restrict__ Qh,
                                                   const bf16_t* __restrict__ Kh,
                                                   float* __restrict__ L) {
  __shared__ __align__(16) bf16_t As[128 * 64];
  __shared__ __align__(16) bf16_t Bs[128 * 64];
  const int n0 = blockIdx.x * 128;
  const int m0 = blockIdx.y * 128;
  const int h = blockIdx.z >> 3;
  const int kseg = blockIdx.z & 7;
  const bf16_t* A = Qh + (size_t)h * (256 * 8192);
  const bf16_t* B = Kh + (size_t)h * (256 * 8192);
  vf4 acc[4][4];
  zero_acc(acc);
  gemm_mainloop(A, 8192, m0, B, 8192, n0, kseg * 1024, kseg * 1024 + 1024, As, Bs, acc);

  const int lane = threadIdx.x & 63;
  const int wave = threadIdx.x >> 6;
  const int wm0 = (wave >> 1) * 64;
  const int wn0 = (wave & 1) * 64;
  const int col = lane & 15;
  const int rq = (lane >> 4) * 4;
  float* Lh = L + (size_t)h * 65536;
#pragma unroll
  for (int mt = 0; mt < 4; ++mt)
#pragma unroll
    for (int nt = 0; nt < 4; ++nt) {
      const int n = n0 + wn0 + nt * 16 + col;
#pragma unroll
      for (int i = 0; i < 4; ++i) {
        const int m = m0 + wm0 + mt * 16 + rq + i;
        atomicAdd(&Lh[(size_t)m * 256 + n], acc[mt][nt][i]);
      }
    }
}

// ---------------------------------------------------------------------------
// Softmax over j: one wave per row (12*256 = 3072 rows)
// ---------------------------------------------------------------------------
__global__ __launch_bounds__(256) void softmax_k(const float* __restrict__ L,
                                                 bf16_t* __restrict__ P) {
  const int row = blockIdx.x * 4 + (threadIdx.x >> 6);
  const int lane = threadIdx.x & 63;
  const float4 v4 = ((const float4*)(L + (size_t)row * 256))[lane];
  float a = v4.x, b = v4.y, c = v4.z, d = v4.w;
  float mx = fmaxf(fmaxf(a, b), fmaxf(c, d));
#pragma unroll
  for (int off = 32; off; off >>= 1) mx = fmaxf(mx, __shfl_xor(mx, off));
  a = expf(a - mx); b = expf(b - mx); c = expf(c - mx); d = expf(d - mx);
  float s = a + b + c + d;
#pragma unroll
  for (int off = 32; off; off >>= 1) s += __shfl_xor(s, off);
  const float inv = 1.0f / s;
  vbf4 o;
  o[0] = (bf16_t)(a * inv); o[1] = (bf16_t)(b * inv);
  o[2] = (bf16_t)(c * inv); o[3] = (bf16_t)(d * inv);
  ((vbf4*)(P + (size_t)row * 256))[lane] = o;
}

// ---------------------------------------------------------------------------
// Context: Ctx[i][rd] = sum_j P[h][i][j] * Vt[h][rd][j]; token-major output
// ---------------------------------------------------------------------------
__global__ __launch_bounds__(256) void ctx_gemm(const bf16_t* __restrict__ P,
                                                const bf16_t* __restrict__ Vt,
                                                bf16_t* __restrict__ CtxTok) {
  __shared__ __align__(16) bf16_t As[128 * 64];
  __shared__ __align__(16) bf16_t Bs[128 * 64];
  const int m0 = blockIdx.x * 128;
  const int n0 = blockIdx.y * 128;
  const int h = blockIdx.z;
  const bf16_t* A = P + (size_t)h * 65536;
  const bf16_t* B = Vt + (size_t)h * 2097152;
  vf4 acc[4][4];
  zero_acc(acc);
  gemm_mainloop(A, 256, m0, B, 256, n0, 0, 256, As, Bs, acc);

  const int lane = threadIdx.x & 63;
  const int wave = threadIdx.x >> 6;
  const int wm0 = (wave >> 1) * 64;
  const int wn0 = (wave & 1) * 64;
  const int col = lane & 15;
  const int rq = (lane >> 4) * 4;
#pragma unroll
  for (int mt = 0; mt < 4; ++mt)
#pragma unroll
    for (int nt = 0; nt < 4; ++nt) {
      const int n = n0 + wn0 + nt * 16 + col;
      const int r = n >> 6, d = n & 63;
#pragma unroll
      for (int i = 0; i < 4; ++i) {
        const int m = m0 + wm0 + mt * 16 + rq + i;
        CtxTok[(size_t)((r << 8) + m) * 768 + (h << 6) + d] = (bf16_t)acc[mt][nt][i];
      }
    }
}

// ---------------------------------------------------------------------------
// Output projection, 1-D swizzled grid: bx -> (m, n), 6 n-blocks per m adjacent
// ---------------------------------------------------------------------------
__global__ __launch_bounds__(256) void out_gemm(const bf16_t* __restrict__ Ctx,
                                                const bf16_t* __restrict__ Wo,
                                                const float* __restrict__ bo,
                                                float* __restrict__ Out) {
  __shared__ __align__(16) bf16_t As[128 * 64];
  __shared__ __align__(16) bf16_t Bs[128 * 64];
  const int bx = blockIdx.x;
  const int m_idx = bx / 6;
  const int n_idx = bx - m_idx * 6;
  const int m0 = m_idx * 128;
  const int n0 = n_idx * 128;
  vf4 acc[4][4];
  zero_acc(acc);
  gemm_mainloop(Ctx, 768, m0, Wo, 768, n0, 0, 768, As, Bs, acc);

  const int lane = threadIdx.x & 63;
  const int wave = threadIdx.x >> 6;
  const int wm0 = (wave >> 1) * 64;
  const int wn0 = (wave & 1) * 64;
  const int col = lane & 15;
  const int rq = (lane >> 4) * 4;
#pragma unroll
  for (int mt = 0; mt < 4; ++mt)
#pragma unroll
    for (int nt = 0; nt < 4; ++nt) {
      const int n = n0 + wn0 + nt * 16 + col;
      const float bb = bo[n];
#pragma unroll
      for (int i = 0; i < 4; ++i) {
        const int m = m0 + wm0 + mt * 16 + rq + i;
        Out[(size_t)m * 768 + n] = acc[mt][nt][i] + bb;
      }
    }
}

// ---------------------------------------------------------------------------
extern "C" void kernel_launch(void* const* d_in, const int* in_sizes, int n_in,
                              void* d_out, int out_size, void* d_ws, size_t ws_size,
                              hipStream_t stream) {
  const float* x  = (const float*)d_in[0];
  const float* wq = (const float*)d_in[1];
  const float* bq = (const float*)d_in[2];
  const float* wk = (const float*)d_in[3];
  const float* bk = (const float*)d_in[4];
  const float* wv = (const float*)d_in[5];
  const float* bv = (const float*)d_in[6];
  const float* wo = (const float*)d_in[7];
  const float* bo = (const float*)d_in[8];
  float* out = (float*)d_out;

  char* ws = (char*)d_ws;
  bf16_t* Xb  = (bf16_t*)(ws + OFF_XB);
  bf16_t* Ctx = (bf16_t*)(ws + OFF_XB);   // alias: Xb dead after QKV
  bf16_t* Qh  = (bf16_t*)(ws + OFF_Q);
  bf16_t* Kh  = (bf16_t*)(ws + OFF_K);
  bf16_t* Vt  = (bf16_t*)(ws + OFF_VT);
  float*  L   = (float*)(ws + OFF_L);
  bf16_t* P   = (bf16_t*)(ws + OFF_P);
  bf16_t* Wq  = (bf16_t*)(ws + OFF_WQ);
  bf16_t* Wk  = (bf16_t*)(ws + OFF_WK);
  bf16_t* Wv  = (bf16_t*)(ws + OFF_WV);
  bf16_t* Wo  = (bf16_t*)(ws + OFF_WO);

  const float scaling = 0.125f / sqrtf(128.0f);  // D^-0.5 / sqrt(R)

  hipMemsetAsync(L, 0, (size_t)12 * 256 * 256 * 4, stream);
  pack_x<<<24576, 256, 0, stream>>>(x, Xb);
  pack_w<<<dim3(2304, 4), 256, 0, stream>>>(wq, wk, wv, wo, Wq, Wk, Wv, Wo, scaling);
  qkv_gemm<<<4608, 256, 0, stream>>>(Xb, Wq, Wk, Wv, bq, bk, bv, Qh, Kh, Vt, scaling);
  logits_gemm<<<dim3(2, 2, 96), 256, 0, stream>>>(Qh, Kh, L);
  softmax_k<<<768, 256, 0, stream>>>(L, P);
  ctx_gemm<<<dim3(2, 64, 12), 256, 0, stream>>>(P, Vt, Ctx);
  out_gemm<<<1536, 256, 0, stream>>>(Ctx, Wo, bo, out);

  (void)in_sizes; (void)n_in; (void)out_size; (void)ws_size;
}

// Round 3
// 455.370 us; speedup vs baseline: 1.1706x; 1.0952x over previous
//
#include <hip/hip_runtime.h>
#include <hip/hip_bf16.h>
#include <math.h>

typedef __bf16 bf16_t;
typedef __bf16 vbf4 __attribute__((ext_vector_type(4)));
typedef __bf16 vbf8 __attribute__((ext_vector_type(8)));
typedef float  vf4  __attribute__((ext_vector_type(4)));

// Workspace layout (bytes). Total = 207,618,048 (~198 MB)
// OFF_XB region is triple-used (stream-ordered): Xb -> Lp partials -> CtxTok
#define OFF_XB   0ull                 // Xb bf16 [32768][768] = 50331648
                                      //  = Lp f32 [16][12][256][256] (logits partials)
                                      //  = CtxTok bf16 [32768][768]
#define OFF_Q    50331648ull          // Qh bf16 [12][256][8192]
#define OFF_K    100663296ull         // Kh bf16 [12][256][8192]
#define OFF_VT   150994944ull         // Vt bf16 [12][8192][256]
#define OFF_P    201326592ull         // P  bf16 [12][256][256]
#define OFF_WQ   202899456ull         // WqT bf16 [768][768] (pre-scaled)
#define OFF_WK   204079104ull
#define OFF_WV   205258752ull
#define OFF_WO   206438400ull

// ---------------------------------------------------------------------------
// Staging: ROWS x 64 bf16 tile via global_load_lds width=16, XOR-swizzled:
// LDS[r][chunk j] holds global chunk (j ^ (r&7)).
// ---------------------------------------------------------------------------
template <int ROWS>
__device__ __forceinline__ void stage_tile(const bf16_t* __restrict__ g,
                                           int ld, int row0, int k0,
                                           bf16_t* lds, int tid) {
  const int wave = tid >> 6;
  const int lane = tid & 63;
  const int js = (lane & 7) ^ (lane >> 3);
#pragma unroll
  for (int cc = 0; cc < ROWS / 32; ++cc) {
    const int chunk = cc * 4 + wave;
    const int row = chunk * 8 + (lane >> 3);
    const bf16_t* gp = g + (size_t)(row0 + row) * ld + k0 + js * 8;
    bf16_t* lp = lds + chunk * 512 + lane * 8;
    __builtin_amdgcn_global_load_lds(
        (const __attribute__((address_space(1))) void*)gp,
        (__attribute__((address_space(3))) void*)lp, 16, 0, 0);
  }
}

__device__ __forceinline__ vbf8 lds_frag(const bf16_t* s, int rr, int ko) {
  const int c = (ko >> 3) ^ (rr & 7);
  return *(const vbf8*)&s[rr * 64 + (c << 3)];
}

// ---------------------------------------------------------------------------
// 128x128 mainloop (4 waves, 4x4 tiles/wave) — used by logits
// ---------------------------------------------------------------------------
__device__ __forceinline__ void gemm_mainloop128(const bf16_t* __restrict__ A, int lda, int m0,
                                                 const bf16_t* __restrict__ Bt, int ldb, int n0,
                                                 int kbeg, int kend,
                                                 bf16_t* As, bf16_t* Bs,
                                                 vf4 (&acc)[4][4]) {
  const int tid = threadIdx.x;
  const int lane = tid & 63;
  const int wave = tid >> 6;
  const int wm0 = (wave >> 1) * 64;
  const int wn0 = (wave & 1) * 64;
  const int fm = lane & 15;
  const int fk = (lane >> 4) * 8;
  for (int k0 = kbeg; k0 < kend; k0 += 64) {
    stage_tile<128>(A, lda, m0, k0, As, tid);
    stage_tile<128>(Bt, ldb, n0, k0, Bs, tid);
    __syncthreads();
#pragma unroll
    for (int kk = 0; kk < 64; kk += 32) {
      vbf8 af[4], bfv[4];
#pragma unroll
      for (int mt = 0; mt < 4; ++mt) af[mt] = lds_frag(As, wm0 + mt * 16 + fm, kk + fk);
#pragma unroll
      for (int nt = 0; nt < 4; ++nt) bfv[nt] = lds_frag(Bs, wn0 + nt * 16 + fm, kk + fk);
#pragma unroll
      for (int mt = 0; mt < 4; ++mt)
#pragma unroll
        for (int nt = 0; nt < 4; ++nt)
          acc[mt][nt] = __builtin_amdgcn_mfma_f32_16x16x32_bf16(af[mt], bfv[nt],
                                                                acc[mt][nt], 0, 0, 0);
    }
    __syncthreads();
  }
}

// ---------------------------------------------------------------------------
// 256x128 mainloop (4 waves, 8x4 tiles/wave: two 64-row quadrants per wave).
// Doubles MFMA per staged byte / per barrier vs 128x128.
// ---------------------------------------------------------------------------
__device__ __forceinline__ void gemm_mainloop256(const bf16_t* __restrict__ A, int lda, int m0,
                                                 const bf16_t* __restrict__ Bt, int ldb, int n0,
                                                 int kbeg, int kend,
                                                 bf16_t* As, bf16_t* Bs,
                                                 vf4 (&acc)[8][4]) {
  const int tid = threadIdx.x;
  const int lane = tid & 63;
  const int wave = tid >> 6;
  const int wq0 = (wave >> 1) * 64;
  const int wn0 = (wave & 1) * 64;
  const int fm = lane & 15;
  const int fk = (lane >> 4) * 8;
  for (int k0 = kbeg; k0 < kend; k0 += 64) {
    stage_tile<256>(A, lda, m0, k0, As, tid);
    stage_tile<128>(Bt, ldb, n0, k0, Bs, tid);
    __syncthreads();
#pragma unroll
    for (int kk = 0; kk < 64; kk += 32) {
      vbf8 af[8], bfv[4];
#pragma unroll
      for (int mt = 0; mt < 8; ++mt) {
        const int rr = ((mt & 4) << 5) + wq0 + (mt & 3) * 16 + fm;  // +128 for mt>=4
        af[mt] = lds_frag(As, rr, kk + fk);
      }
#pragma unroll
      for (int nt = 0; nt < 4; ++nt) bfv[nt] = lds_frag(Bs, wn0 + nt * 16 + fm, kk + fk);
#pragma unroll
      for (int mt = 0; mt < 8; ++mt)
#pragma unroll
        for (int nt = 0; nt < 4; ++nt)
          acc[mt][nt] = __builtin_amdgcn_mfma_f32_16x16x32_bf16(af[mt], bfv[nt],
                                                                acc[mt][nt], 0, 0, 0);
    }
    __syncthreads();
  }
}

__device__ __forceinline__ void zero_acc4(vf4 (&acc)[4][4]) {
  const vf4 z = {0.f, 0.f, 0.f, 0.f};
#pragma unroll
  for (int mt = 0; mt < 4; ++mt)
#pragma unroll
    for (int nt = 0; nt < 4; ++nt) acc[mt][nt] = z;
}
__device__ __forceinline__ void zero_acc8(vf4 (&acc)[8][4]) {
  const vf4 z = {0.f, 0.f, 0.f, 0.f};
#pragma unroll
  for (int mt = 0; mt < 8; ++mt)
#pragma unroll
    for (int nt = 0; nt < 4; ++nt) acc[mt][nt] = z;
}

// ---------------------------------------------------------------------------
// Pack kernels
// ---------------------------------------------------------------------------
__global__ __launch_bounds__(256) void pack_x(const float* __restrict__ x,
                                              bf16_t* __restrict__ Xb) {
  const size_t idx = (size_t)blockIdx.x * 256 + threadIdx.x;
  const float4 v = ((const float4*)x)[idx];
  vbf4 o;
  o[0] = (bf16_t)v.x; o[1] = (bf16_t)v.y; o[2] = (bf16_t)v.z; o[3] = (bf16_t)v.w;
  ((vbf4*)Xb)[idx] = o;
}

// LDS-tiled transpose: 64x64 tile, coalesced read and write
__global__ __launch_bounds__(256) void pack_w(const float* __restrict__ wq,
                                              const float* __restrict__ wk,
                                              const float* __restrict__ wv,
                                              const float* __restrict__ wo,
                                              bf16_t* __restrict__ Wq, bf16_t* __restrict__ Wk,
                                              bf16_t* __restrict__ Wv, bf16_t* __restrict__ Wo,
                                              float scaling) {
  __shared__ float t[64][65];
  const int wid = blockIdx.y;
  const float* src = (wid == 0) ? wq : (wid == 1) ? wk : (wid == 2) ? wv : wo;
  bf16_t* dst = (wid == 0) ? Wq : (wid == 1) ? Wk : (wid == 2) ? Wv : Wo;
  const float sc = (wid == 0) ? scaling : 1.0f;
  const int kt = (blockIdx.x / 12) * 64;
  const int nt = (blockIdx.x % 12) * 64;
  const int tx = threadIdx.x & 63;
  const int ty = threadIdx.x >> 6;
#pragma unroll
  for (int p = 0; p < 16; ++p) {
    const int k = ty + p * 4;
    t[tx][k] = src[(size_t)(kt + k) * 768 + nt + tx] * sc;
  }
  __syncthreads();
#pragma unroll
  for (int p = 0; p < 16; ++p) {
    const int n = ty + p * 4;
    dst[(size_t)(nt + n) * 768 + kt + tx] = (bf16_t)t[n][tx];
  }
}

// ---------------------------------------------------------------------------
// QKV projection: 256x128 tiles. bx -> (m_idx, n_idx, z); 18 blocks sharing an
// A-tile adjacent. z=0 Q head-major, z=1 K head-major, z=2 V transposed.
// ---------------------------------------------------------------------------
__global__ __launch_bounds__(256, 2) void qkv_gemm(const bf16_t* __restrict__ Xb,
                                                   const bf16_t* __restrict__ Wq,
                                                   const bf16_t* __restrict__ Wk,
                                                   const bf16_t* __restrict__ Wv,
                                                   const float* __restrict__ bq,
                                                   const float* __restrict__ bk,
                                                   const float* __restrict__ bv,
                                                   bf16_t* __restrict__ Qh,
                                                   bf16_t* __restrict__ Kh,
                                                   bf16_t* __restrict__ Vt,
                                                   float scaling) {
  __shared__ __align__(16) bf16_t As[256 * 64];
  __shared__ __align__(16) bf16_t Bs[128 * 64];
  const int bx = blockIdx.x;
  const int m_idx = bx / 18;
  const int rem = bx - m_idx * 18;
  const int n_idx = rem / 3;
  const int z = rem - n_idx * 3;
  const int m0 = m_idx * 256;
  const int n0 = n_idx * 128;
  const bf16_t* W = (z == 0) ? Wq : (z == 1) ? Wk : Wv;
  vf4 acc[8][4];
  zero_acc8(acc);
  gemm_mainloop256(Xb, 768, m0, W, 768, n0, 0, 768, As, Bs, acc);

  const int lane = threadIdx.x & 63;
  const int wave = threadIdx.x >> 6;
  const int wq0 = (wave >> 1) * 64;
  const int wn0 = (wave & 1) * 64;
  const int col = lane & 15;
  const int rq = (lane >> 4) * 4;
  const float* bias = (z == 0) ? bq : (z == 1) ? bk : bv;
  const float bsc = (z == 0) ? scaling : 1.0f;

  if (z < 2) {
    bf16_t* O = (z == 0) ? Qh : Kh;
#pragma unroll
    for (int mt = 0; mt < 8; ++mt) {
#pragma unroll
      for (int nt = 0; nt < 4; ++nt) {
        const int n = n0 + wn0 + nt * 16 + col;
        const int h = n >> 6, d = n & 63;
        const float bb = bias[n] * bsc;
#pragma unroll
        for (int i = 0; i < 4; ++i) {
          const int m = m0 + ((mt & 4) << 5) + wq0 + (mt & 3) * 16 + rq + i;
          const int r = m >> 8, c = m & 255;
          O[(size_t)(h * 256 + c) * 8192 + (r << 6) + d] = (bf16_t)(acc[mt][nt][i] + bb);
        }
      }
    }
  } else {
#pragma unroll
    for (int mt = 0; mt < 8; ++mt) {
      const int mb = m0 + ((mt & 4) << 5) + wq0 + (mt & 3) * 16 + rq;
      const int r = mb >> 8, c = mb & 255;
#pragma unroll
      for (int nt = 0; nt < 4; ++nt) {
        const int n = n0 + wn0 + nt * 16 + col;
        const int h = n >> 6, d = n & 63;
        const float bb = bias[n];
        vbf4 pk;
#pragma unroll
        for (int i = 0; i < 4; ++i) pk[i] = (bf16_t)(acc[mt][nt][i] + bb);
        *(vbf4*)&Vt[(size_t)h * 2097152 + ((size_t)((r << 6) + d)) * 256 + c] = pk;
      }
    }
  }
}

// ---------------------------------------------------------------------------
// Logits: split-K x16, NON-ATOMIC partials Lp[kseg][h][i][j]
// grid (2, 2, 192): z = h*16 + kseg
// ---------------------------------------------------------------------------
__global__ __launch_bounds__(256) void logits_gemm(const bf16_t* __restrict__ Qh,
                                                   const bf16_t* __restrict__ Kh,
                                                   float* __restrict__ Lp) {
  __shared__ __align__(16) bf16_t As[128 * 64];
  __shared__ __align__(16) bf16_t Bs[128 * 64];
  const int n0 = blockIdx.x * 128;
  const int m0 = blockIdx.y * 128;
  const int h = blockIdx.z >> 4;
  const int kseg = blockIdx.z & 15;
  const bf16_t* A = Qh + (size_t)h * (256 * 8192);
  const bf16_t* B = Kh + (size_t)h * (256 * 8192);
  vf4 acc[4][4];
  zero_acc4(acc);
  gemm_mainloop128(A, 8192, m0, B, 8192, n0, kseg * 512, kseg * 512 + 512, As, Bs, acc);

  const int lane = threadIdx.x & 63;
  const int wave = threadIdx.x >> 6;
  const int wm0 = (wave >> 1) * 64;
  const int wn0 = (wave & 1) * 64;
  const int col = lane & 15;
  const int rq = (lane >> 4) * 4;
  float* Lph = Lp + ((size_t)(kseg * 12 + h)) * 65536;
#pragma unroll
  for (int mt = 0; mt < 4; ++mt)
#pragma unroll
    for (int nt = 0; nt < 4; ++nt) {
      const int n = n0 + wn0 + nt * 16 + col;
#pragma unroll
      for (int i = 0; i < 4; ++i) {
        const int m = m0 + wm0 + mt * 16 + rq + i;
        Lph[(size_t)m * 256 + n] = acc[mt][nt][i];
      }
    }
}

// ---------------------------------------------------------------------------
// Softmax: reduce 16 partials + softmax over j. One wave per row (3072 rows).
// ---------------------------------------------------------------------------
__global__ __launch_bounds__(256) void softmax_k(const float* __restrict__ Lp,
                                                 bf16_t* __restrict__ P) {
  const int row = blockIdx.x * 4 + (threadIdx.x >> 6);  // h*256 + i
  const int lane = threadIdx.x & 63;
  float a = 0.f, b = 0.f, c = 0.f, d = 0.f;
#pragma unroll
  for (int ks = 0; ks < 16; ++ks) {
    const float4 v4 = ((const float4*)(Lp + (size_t)ks * 786432 + (size_t)row * 256))[lane];
    a += v4.x; b += v4.y; c += v4.z; d += v4.w;
  }
  float mx = fmaxf(fmaxf(a, b), fmaxf(c, d));
#pragma unroll
  for (int off = 32; off; off >>= 1) mx = fmaxf(mx, __shfl_xor(mx, off));
  a = expf(a - mx); b = expf(b - mx); c = expf(c - mx); d = expf(d - mx);
  float s = a + b + c + d;
#pragma unroll
  for (int off = 32; off; off >>= 1) s += __shfl_xor(s, off);
  const float inv = 1.0f / s;
  vbf4 o;
  o[0] = (bf16_t)(a * inv); o[1] = (bf16_t)(b * inv);
  o[2] = (bf16_t)(c * inv); o[3] = (bf16_t)(d * inv);
  ((vbf4*)(P + (size_t)row * 256))[lane] = o;
}

// ---------------------------------------------------------------------------
// Context: 256x128 tile (M=256 exactly). grid (64, 12). Token-major output.
// ---------------------------------------------------------------------------
__global__ __launch_bounds__(256, 2) void ctx_gemm(const bf16_t* __restrict__ P,
                                                   const bf16_t* __restrict__ Vt,
                                                   bf16_t* __restrict__ CtxTok) {
  __shared__ __align__(16) bf16_t As[256 * 64];
  __shared__ __align__(16) bf16_t Bs[128 * 64];
  const int n0 = blockIdx.x * 128;
  const int h = blockIdx.y;
  const bf16_t* A = P + (size_t)h * 65536;
  const bf16_t* B = Vt + (size_t)h * 2097152;
  vf4 acc[8][4];
  zero_acc8(acc);
  gemm_mainloop256(A, 256, 0, B, 256, n0, 0, 256, As, Bs, acc);

  const int lane = threadIdx.x & 63;
  const int wave = threadIdx.x >> 6;
  const int wq0 = (wave >> 1) * 64;
  const int wn0 = (wave & 1) * 64;
  const int col = lane & 15;
  const int rq = (lane >> 4) * 4;
#pragma unroll
  for (int mt = 0; mt < 8; ++mt)
#pragma unroll
    for (int nt = 0; nt < 4; ++nt) {
      const int n = n0 + wn0 + nt * 16 + col;
      const int r = n >> 6, d = n & 63;
#pragma unroll
      for (int i = 0; i < 4; ++i) {
        const int m = ((mt & 4) << 5) + wq0 + (mt & 3) * 16 + rq + i;
        CtxTok[(size_t)((r << 8) + m) * 768 + (h << 6) + d] = (bf16_t)acc[mt][nt][i];
      }
    }
}

// ---------------------------------------------------------------------------
// Output projection: 256x128 tiles, bx -> (m_idx, n_idx)
// ---------------------------------------------------------------------------
__global__ __launch_bounds__(256, 2) void out_gemm(const bf16_t* __restrict__ Ctx,
                                                   const bf16_t* __restrict__ Wo,
                                                   const float* __restrict__ bo,
                                                   float* __restrict__ Out) {
  __shared__ __align__(16) bf16_t As[256 * 64];
  __shared__ __align__(16) bf16_t Bs[128 * 64];
  const int bx = blockIdx.x;
  const int m_idx = bx / 6;
  const int n_idx = bx - m_idx * 6;
  const int m0 = m_idx * 256;
  const int n0 = n_idx * 128;
  vf4 acc[8][4];
  zero_acc8(acc);
  gemm_mainloop256(Ctx, 768, m0, Wo, 768, n0, 0, 768, As, Bs, acc);

  const int lane = threadIdx.x & 63;
  const int wave = threadIdx.x >> 6;
  const int wq0 = (wave >> 1) * 64;
  const int wn0 = (wave & 1) * 64;
  const int col = lane & 15;
  const int rq = (lane >> 4) * 4;
#pragma unroll
  for (int mt = 0; mt < 8; ++mt)
#pragma unroll
    for (int nt = 0; nt < 4; ++nt) {
      const int n = n0 + wn0 + nt * 16 + col;
      const float bb = bo[n];
#pragma unroll
      for (int i = 0; i < 4; ++i) {
        const int m = m0 + ((mt & 4) << 5) + wq0 + (mt & 3) * 16 + rq + i;
        Out[(size_t)m * 768 + n] = acc[mt][nt][i] + bb;
      }
    }
}

// ---------------------------------------------------------------------------
extern "C" void kernel_launch(void* const* d_in, const int* in_sizes, int n_in,
                              void* d_out, int out_size, void* d_ws, size_t ws_size,
                              hipStream_t stream) {
  const float* x  = (const float*)d_in[0];
  const float* wq = (const float*)d_in[1];
  const float* bq = (const float*)d_in[2];
  const float* wk = (const float*)d_in[3];
  const float* bk = (const float*)d_in[4];
  const float* wv = (const float*)d_in[5];
  const float* bv = (const float*)d_in[6];
  const float* wo = (const float*)d_in[7];
  const float* bo = (const float*)d_in[8];
  float* out = (float*)d_out;

  char* ws = (char*)d_ws;
  bf16_t* Xb  = (bf16_t*)(ws + OFF_XB);
  float*  Lp  = (float*)(ws + OFF_XB);    // alias: Xb dead after QKV
  bf16_t* Ctx = (bf16_t*)(ws + OFF_XB);   // alias: Lp dead after softmax
  bf16_t* Qh  = (bf16_t*)(ws + OFF_Q);
  bf16_t* Kh  = (bf16_t*)(ws + OFF_K);
  bf16_t* Vt  = (bf16_t*)(ws + OFF_VT);
  bf16_t* P   = (bf16_t*)(ws + OFF_P);
  bf16_t* Wq  = (bf16_t*)(ws + OFF_WQ);
  bf16_t* Wk  = (bf16_t*)(ws + OFF_WK);
  bf16_t* Wv  = (bf16_t*)(ws + OFF_WV);
  bf16_t* Wo  = (bf16_t*)(ws + OFF_WO);

  const float scaling = 0.125f / sqrtf(128.0f);  // D^-0.5 / sqrt(R)

  pack_x<<<24576, 256, 0, stream>>>(x, Xb);
  pack_w<<<dim3(144, 4), 256, 0, stream>>>(wq, wk, wv, wo, Wq, Wk, Wv, Wo, scaling);
  qkv_gemm<<<2304, 256, 0, stream>>>(Xb, Wq, Wk, Wv, bq, bk, bv, Qh, Kh, Vt, scaling);
  logits_gemm<<<dim3(2, 2, 192), 256, 0, stream>>>(Qh, Kh, Lp);
  softmax_k<<<768, 256, 0, stream>>>(Lp, P);
  ctx_gemm<<<dim3(64, 12), 256, 0, stream>>>(P, Vt, Ctx);
  out_gemm<<<768, 256, 0, stream>>>(Ctx, Wo, bo, out);

  (void)in_sizes; (void)n_in; (void)out_size; (void)ws_size;
}